// Round 5
// baseline (116.392 us; speedup 1.0000x reference)
//
#include <hip/hip_runtime.h>

#define HW      16384      // H*W = 128*128
#define HW4     4096       // HW/4
#define NP      17         // n_parts
#define CCH     34         // channels = (1+TAG_DIM)*n_parts
#define BB      8
#define SS      4
#define NPERS   30
#define NBS     (BB*SS)               // 32
#define DETB    1088                  // det blocks: DITEMS = DETB*256*2 exactly
#define GROUPB  32
#define GRID    (DETB + GROUPB)       // 1120
#define DITEMS  (NP*BB*HW4)           // 557,056 items (b,p,hw4)
#define LOSS_EPS 1e-6f
#define DET_INV (1.0f / 8912896.0f)   // 1/(NBS*NP*HW)

__device__ __forceinline__ float block_reduce_sum(float v, float* sred) {
    __syncthreads();                      // safe for back-to-back calls
    for (int off = 32; off > 0; off >>= 1)
        v += __shfl_down(v, off, 64);
    const int lane = threadIdx.x & 63;
    const int wave = threadIdx.x >> 6;
    if (lane == 0) sred[wave] = v;
    __syncthreads();
    if (threadIdx.x == 0) {
        float s = 0.f;
        for (int i = 0; i < 4; i++) s += sred[i];   // blockDim fixed 256
        sred[0] = s;
    }
    __syncthreads();
    return sred[0];
}

// Single kernel: det blocks and group blocks each contribute one fp32
// atomicAdd to out[0]. No inter-block ordering needed (addition commutes);
// plain device-scope atomicAdd — NO fences (Round-3's acq_rel+threadfence
// protocol caused an L2-writeback storm, 76-100 us for this same work).
__global__ __launch_bounds__(256) void k_main(const float* __restrict__ preds,
                                              const float* __restrict__ masks,
                                              const float* __restrict__ heat,
                                              const int*   __restrict__ kp,
                                              float* __restrict__ out) {
    __shared__ float sred[4];
    __shared__ float sg[NPERS * NP];
    __shared__ float svis[NPERS * NP];
    __shared__ float smean[NPERS];
    __shared__ float scnt[NPERS];
    __shared__ float spull[NPERS];
    __shared__ float snum;

    const int tid = threadIdx.x;
    const int bid = blockIdx.x;

    if (bid < DETB) {
        // ---------------- det phase ----------------
        // item t -> (b,p,hw4); heat/mask loaded once, s-loop over preds.
        float acc = 0.f;
        const int t0 = bid * 256 + tid;
        #pragma unroll
        for (int it = 0; it < 2; ++it) {
            const int t    = t0 + it * (DETB * 256);
            const int hw4  = t & (HW4 - 1);
            const int rest = t >> 12;            // b*NP + p, [0,136)
            const int b    = rest / NP;
            const int p    = rest - b * NP;
            const float4 h = *(const float4*)(heat  + ((size_t)rest) * HW + (size_t)hw4 * 4);
            const float4 m = *(const float4*)(masks + (size_t)b * HW + (size_t)hw4 * 4);
            #pragma unroll
            for (int s = 0; s < SS; s++) {
                const int bs = b * SS + s;
                const float4 d = *(const float4*)(preds + ((size_t)bs * CCH + p) * HW + (size_t)hw4 * 4);
                const float dx = d.x - h.x, dy = d.y - h.y, dz = d.z - h.z, dw = d.w - h.w;
                acc += dx * dx * m.x + dy * dy * m.y + dz * dz * m.z + dw * dw * m.w;
            }
        }
        const float tot = block_reduce_sum(acc, sred);
        if (tid == 0) atomicAdd(out, tot * DET_INV);
    } else {
        // ---------------- group phase: one block per (b,s) ----------------
        const int bs = bid - DETB;
        const int b  = bs >> 2;
        const size_t tag_base = ((size_t)bs * CCH + NP) * HW;

        for (int t = tid; t < NPERS * NP; t += 256) {
            const int kbase = (b * NPERS * NP + t) * 2;
            int ii = kp[kbase];
            const int vv = kp[kbase + 1];
            if (ii < 0) ii = 0;
            if (ii >= NP * HW) ii = NP * HW - 1;   // jnp.take clip semantics
            svis[t] = (vv > 0) ? 1.f : 0.f;
            sg[t]   = preds[tag_base + (size_t)ii];
        }
        __syncthreads();

        if (tid < NPERS) {
            float c = 0.f, msum = 0.f;
            for (int k = 0; k < NP; k++) {
                c    += svis[tid * NP + k];
                msum += sg[tid * NP + k] * svis[tid * NP + k];
            }
            const float sc = fmaxf(c, 1.f);
            const float mu = msum / sc;
            float pp = 0.f;
            for (int k = 0; k < NP; k++) {
                const float dd = sg[tid * NP + k] - mu;
                pp += dd * dd * svis[tid * NP + k];
            }
            scnt[tid]  = c;
            smean[tid] = mu;
            spull[tid] = pp / sc;   // TAG_DIM = 1
        }
        __syncthreads();

        float pull_val = 0.f;     // live only at tid 0
        if (tid == 0) {
            float num = 0.f, psum = 0.f;
            for (int i = 0; i < NPERS; i++)
                if (scnt[i] > 0.f) { num += 1.f; psum += spull[i]; }
            snum = num;
            pull_val = psum / (num + LOSS_EPS);
        }
        __syncthreads();

        float pacc = 0.f;
        for (int t = tid; t < NPERS * NPERS; t += 256) {
            const int i = t / NPERS;
            const int j = t - i * NPERS;
            const float vi = (scnt[i] > 0.f) ? 1.f : 0.f;
            const float vj = (scnt[j] > 0.f) ? 1.f : 0.f;
            const float d = smean[i] - smean[j];
            pacc += expf(-d * d) * vi * vj;
        }
        const float ptot = block_reduce_sum(pacc, sred);
        if (tid == 0) {
            const float num = snum;
            const float push_val = (ptot - num) / ((num - 1.f) * num + LOSS_EPS) * 0.5f;
            atomicAdd(out, 0.001f * (pull_val + push_val) * (1.0f / (float)NBS));
        }
    }
}

extern "C" void kernel_launch(void* const* d_in, const int* in_sizes, int n_in,
                              void* d_out, int out_size, void* d_ws, size_t ws_size,
                              hipStream_t stream) {
    const float* preds = (const float*)d_in[0];
    const float* masks = (const float*)d_in[1];
    const float* heat  = (const float*)d_in[2];
    const int*   kp    = (const int*)d_in[3];
    float* out = (float*)d_out;

    hipMemsetAsync(d_out, 0, (size_t)out_size * sizeof(float), stream);  // poison -> 0
    k_main<<<GRID, 256, 0, stream>>>(preds, masks, heat, kp, out);
}

// Round 6
// 107.355 us; speedup vs baseline: 1.0842x; 1.0842x over previous
//
#include <hip/hip_runtime.h>

#define HW      16384      // H*W = 128*128
#define HW4     4096       // HW/4
#define NP      17         // n_parts
#define CCH     34         // channels = (1+TAG_DIM)*n_parts
#define BB      8
#define SS      4
#define NPERS   30
#define NBS     (BB*SS)               // 32
#define DETB    1088                  // det blocks: DITEMS = DETB*256*2 exactly
#define GROUPB  32
#define GRID    (DETB + GROUPB)       // 1120
#define DITEMS  (NP*BB*HW4)           // 557,056 items (b,p,hw4)
#define LOSS_EPS 1e-6f

// d_ws layout (floats): [0 .. 1088) det partials | [1088 .. 1152) pull[32] ++ push[32]
#define WS_PP   DETB

__device__ __forceinline__ float block_reduce_sum(float v, float* sred) {
    __syncthreads();                      // safe for back-to-back calls
    for (int off = 32; off > 0; off >>= 1)
        v += __shfl_down(v, off, 64);
    const int lane = threadIdx.x & 63;
    const int wave = threadIdx.x >> 6;
    if (lane == 0) sred[wave] = v;
    __syncthreads();
    if (threadIdx.x == 0) {
        float s = 0.f;
        for (int i = 0; i < 4; i++) s += sred[i];   // blockDim fixed 256
        sred[0] = s;
    }
    __syncthreads();
    return sred[0];
}

// Two kernels, kernel-boundary ordering only. NO inter-block fences/atomics:
//  - Round 3 (threadfence+acq_rel protocol): L2-writeback storm, 76-100 us.
//  - Round 5 (1120 atomicAdds to out[0]): serialized atomic tail, +8 us.
// Group blocks are bid 0..31 (dispatched first -> latency chain starts early).
__global__ __launch_bounds__(256) void k_main(const float* __restrict__ preds,
                                              const float* __restrict__ masks,
                                              const float* __restrict__ heat,
                                              const int*   __restrict__ kp,
                                              float* __restrict__ ws) {
    __shared__ float sred[4];
    __shared__ float sg[NPERS * NP];
    __shared__ float svis[NPERS * NP];
    __shared__ float smean[NPERS];
    __shared__ float scnt[NPERS];
    __shared__ float spull[NPERS];
    __shared__ float snum;

    const int tid = threadIdx.x;
    const int bid = blockIdx.x;

    if (bid >= GROUPB) {
        // ---------------- det phase: blocks 32..1119 ----------------
        // item t -> (b,p,hw4); heat/mask loaded once, s-loop over preds.
        float acc = 0.f;
        const int t0 = (bid - GROUPB) * 256 + tid;
        #pragma unroll
        for (int it = 0; it < 2; ++it) {
            const int t    = t0 + it * (DETB * 256);
            const int hw4  = t & (HW4 - 1);
            const int rest = t >> 12;            // b*NP + p, [0,136)
            const int b    = rest / NP;
            const int p    = rest - b * NP;
            const float4 h = *(const float4*)(heat  + ((size_t)rest) * HW + (size_t)hw4 * 4);
            const float4 m = *(const float4*)(masks + (size_t)b * HW + (size_t)hw4 * 4);
            #pragma unroll
            for (int s = 0; s < SS; s++) {
                const int bs = b * SS + s;
                const float4 d = *(const float4*)(preds + ((size_t)bs * CCH + p) * HW + (size_t)hw4 * 4);
                const float dx = d.x - h.x, dy = d.y - h.y, dz = d.z - h.z, dw = d.w - h.w;
                acc += dx * dx * m.x + dy * dy * m.y + dz * dz * m.z + dw * dw * m.w;
            }
        }
        const float tot = block_reduce_sum(acc, sred);
        if (tid == 0) ws[bid - GROUPB] = tot;
    } else {
        // ---------------- group phase: blocks 0..31, one per (b,s) ----------------
        const int bs = bid;
        const int b  = bs >> 2;
        const size_t tag_base = ((size_t)bs * CCH + NP) * HW;

        for (int t = tid; t < NPERS * NP; t += 256) {
            const int kbase = (b * NPERS * NP + t) * 2;
            int ii = kp[kbase];
            const int vv = kp[kbase + 1];
            if (ii < 0) ii = 0;
            if (ii >= NP * HW) ii = NP * HW - 1;   // jnp.take clip semantics
            svis[t] = (vv > 0) ? 1.f : 0.f;
            sg[t]   = preds[tag_base + (size_t)ii];
        }
        __syncthreads();

        if (tid < NPERS) {
            float c = 0.f, msum = 0.f;
            for (int k = 0; k < NP; k++) {
                c    += svis[tid * NP + k];
                msum += sg[tid * NP + k] * svis[tid * NP + k];
            }
            const float sc = fmaxf(c, 1.f);
            const float mu = msum / sc;
            float pp = 0.f;
            for (int k = 0; k < NP; k++) {
                const float dd = sg[tid * NP + k] - mu;
                pp += dd * dd * svis[tid * NP + k];
            }
            scnt[tid]  = c;
            smean[tid] = mu;
            spull[tid] = pp / sc;   // TAG_DIM = 1
        }
        __syncthreads();

        if (tid == 0) {
            float num = 0.f, psum = 0.f;
            for (int i = 0; i < NPERS; i++)
                if (scnt[i] > 0.f) { num += 1.f; psum += spull[i]; }
            snum = num;
            ws[WS_PP + bs] = psum / (num + LOSS_EPS);     // pull
        }
        __syncthreads();

        float pacc = 0.f;
        for (int t = tid; t < NPERS * NPERS; t += 256) {
            const int i = t / NPERS;
            const int j = t - i * NPERS;
            const float vi = (scnt[i] > 0.f) ? 1.f : 0.f;
            const float vj = (scnt[j] > 0.f) ? 1.f : 0.f;
            const float d = smean[i] - smean[j];
            pacc += expf(-d * d) * vi * vj;
        }
        const float ptot = block_reduce_sum(pacc, sred);
        if (tid == 0) {
            const float num = snum;
            ws[WS_PP + NBS + bs] = (ptot - num) / ((num - 1.f) * num + LOSS_EPS) * 0.5f;  // push
        }
    }
}

__global__ __launch_bounds__(256) void k_final(const float* __restrict__ ws,
                                               float* __restrict__ out) {
    __shared__ float sred[4];
    float a = 0.f;
    for (int i = threadIdx.x; i < DETB; i += 256) a += ws[i];
    const float det_sum = block_reduce_sum(a, sred);
    float pp = 0.f;
    if (threadIdx.x < 2 * NBS) pp = ws[WS_PP + threadIdx.x];
    const float pp_sum = block_reduce_sum(pp, sred);
    if (threadIdx.x == 0) {
        const float det_mean = det_sum / (float)((size_t)NBS * NP * HW);  // / 8,912,896
        out[0] = 0.001f * (pp_sum / (float)NBS) + det_mean;
    }
}

extern "C" void kernel_launch(void* const* d_in, const int* in_sizes, int n_in,
                              void* d_out, int out_size, void* d_ws, size_t ws_size,
                              hipStream_t stream) {
    const float* preds = (const float*)d_in[0];
    const float* masks = (const float*)d_in[1];
    const float* heat  = (const float*)d_in[2];
    const int*   kp    = (const int*)d_in[3];
    float* out = (float*)d_out;
    float* ws  = (float*)d_ws;

    k_main<<<GRID, 256, 0, stream>>>(preds, masks, heat, kp, ws);
    k_final<<<1, 256, 0, stream>>>(ws, out);
}